// Round 8
// baseline (470.000 us; speedup 1.0000x reference)
//
#include <hip/hip_runtime.h>

#define IN_DIM 128
#define OUT_DIM 64
#define PADK 136    // gemm LDS row stride (bf16 elems)
#define RT 128      // rows per partition (tile)
#define RTSH 7      // log2(RT)
#define BT 512      // bagg threads (8 waves)

typedef float f32x4 __attribute__((ext_vector_type(4)));
typedef short bf16x8 __attribute__((ext_vector_type(8)));

__device__ __forceinline__ unsigned short f2bf(float f) {   // RNE f32->bf16
    unsigned u = __float_as_uint(f);
    return (unsigned short)((u + 0x7FFFu + ((u >> 16) & 1u)) >> 16);
}
__device__ __forceinline__ float bf2f(unsigned short h) {
    return __uint_as_float((unsigned)h << 16);
}

// ---------------------------------------------------------------------------
// GEMM device body: xw = x@W via split-bf16 MFMA (hi*hi + hi*lo + lo*hi),
// 64 rows per block `blk`.  Shared by gemm_and_hist and gemm_only.
// ---------------------------------------------------------------------------
__device__ __forceinline__ void gemm_body(const float* __restrict__ x,
                                          const float* __restrict__ w,
                                          float* __restrict__ xw, int N, int blk) {
    __shared__ unsigned short Ahi[64 * PADK];
    __shared__ unsigned short Alo[64 * PADK];
    __shared__ unsigned short Bhi[64 * PADK];   // W^T: [c][k]
    __shared__ unsigned short Blo[64 * PADK];

    const int t = threadIdx.x;
    const int r0 = blk * 64;

    {   // stage W^T hi/lo
        const int c = t >> 2;
        const int kb = (t & 3) * 32;
        for (int k4 = 0; k4 < 32; k4 += 4) {
            ushort4 h, l;
            float v0 = w[(kb + k4 + 0) * OUT_DIM + c];
            float v1 = w[(kb + k4 + 1) * OUT_DIM + c];
            float v2 = w[(kb + k4 + 2) * OUT_DIM + c];
            float v3 = w[(kb + k4 + 3) * OUT_DIM + c];
            h.x = f2bf(v0); l.x = f2bf(v0 - bf2f(h.x));
            h.y = f2bf(v1); l.y = f2bf(v1 - bf2f(h.y));
            h.z = f2bf(v2); l.z = f2bf(v2 - bf2f(h.z));
            h.w = f2bf(v3); l.w = f2bf(v3 - bf2f(h.w));
            *(ushort4*)&Bhi[c * PADK + kb + k4] = h;
            *(ushort4*)&Blo[c * PADK + kb + k4] = l;
        }
    }
    {   // stage x rows hi/lo
        const float4* x4 = (const float4*)x;
        for (int i = 0; i < 8; ++i) {
            const int f = i * 256 + t;
            const int rr = f >> 5;
            const int kk = (f & 31) * 4;
            int row = r0 + rr; if (row >= N) row = N - 1;
            float4 v = x4[(size_t)row * (IN_DIM / 4) + (kk >> 2)];
            ushort4 h, l;
            h.x = f2bf(v.x); l.x = f2bf(v.x - bf2f(h.x));
            h.y = f2bf(v.y); l.y = f2bf(v.y - bf2f(h.y));
            h.z = f2bf(v.z); l.z = f2bf(v.z - bf2f(h.z));
            h.w = f2bf(v.w); l.w = f2bf(v.w - bf2f(h.w));
            *(ushort4*)&Ahi[rr * PADK + kk] = h;
            *(ushort4*)&Alo[rr * PADK + kk] = l;
        }
    }
    __syncthreads();

    const int lane = t & 63;
    const int wv = t >> 6;
    const int m = lane & 15;
    const int quad = lane >> 4;

    bf16x8 ahi[4], alo[4];
#pragma unroll
    for (int ks = 0; ks < 4; ++ks) {
        const int off = (wv * 16 + m) * PADK + ks * 32 + quad * 8;
        ahi[ks] = *(const bf16x8*)&Ahi[off];
        alo[ks] = *(const bf16x8*)&Alo[off];
    }
#pragma unroll
    for (int ct = 0; ct < 4; ++ct) {
        f32x4 acc = {0.f, 0.f, 0.f, 0.f};
#pragma unroll
        for (int ks = 0; ks < 4; ++ks) {
            const int off = (ct * 16 + m) * PADK + ks * 32 + quad * 8;
            bf16x8 bh = *(const bf16x8*)&Bhi[off];
            bf16x8 bl = *(const bf16x8*)&Blo[off];
            acc = __builtin_amdgcn_mfma_f32_16x16x32_bf16(alo[ks], bh, acc, 0, 0, 0);
            acc = __builtin_amdgcn_mfma_f32_16x16x32_bf16(ahi[ks], bl, acc, 0, 0, 0);
            acc = __builtin_amdgcn_mfma_f32_16x16x32_bf16(ahi[ks], bh, acc, 0, 0, 0);
        }
#pragma unroll
        for (int i = 0; i < 4; ++i) {
            const int row = r0 + wv * 16 + quad * 4 + i;
            if (row < N) xw[(size_t)row * OUT_DIM + ct * 16 + m] = acc[i];
        }
    }
}

// ---------------------------------------------------------------------------
// K1: blocks [0,GB) run the GEMM; blocks [GB,GB+256) histogram edge
// destination partitions (LDS hist -> P global atomics per block).
// ---------------------------------------------------------------------------
__global__ __launch_bounds__(256) void gemm_and_hist(
        const float* __restrict__ x, const float* __restrict__ w,
        float* __restrict__ xw, int N,
        const int* __restrict__ arow, int* __restrict__ pcount, int E, int GB) {
    if ((int)blockIdx.x < GB) {
        gemm_body(x, w, xw, N, blockIdx.x);
    } else {
        __shared__ int cnt[1024];
        const int P = (N + RT - 1) >> RTSH;
        const int t = threadIdx.x;
        for (int i = t; i < P; i += 256) cnt[i] = 0;
        __syncthreads();
        const int hb = blockIdx.x - GB;              // 0..255
        for (int e = hb * 256 + t; e < E; e += 256 * 256)
            atomicAdd(&cnt[arow[e] >> RTSH], 1);
        __syncthreads();
        for (int i = t; i < P; i += 256)
            if (cnt[i]) atomicAdd(&pcount[i], cnt[i]);
    }
}

// ---------------------------------------------------------------------------
// K2: exclusive scan of P partition counts (P <= 1024).
// ---------------------------------------------------------------------------
__global__ __launch_bounds__(256) void pscan(const int* __restrict__ pcount,
                                             int* __restrict__ pbase,
                                             int* __restrict__ pcursor, int P) {
    __shared__ int tmp[1024];
    const int t = threadIdx.x;
    for (int i = t; i < P; i += 256) tmp[i] = pcount[i];
    __syncthreads();
    if (t == 0) {
        int run = 0;
        for (int i = 0; i < P; ++i) { int v = tmp[i]; tmp[i] = run; run += v; }
    }
    __syncthreads();
    for (int i = t; i < P; i += 256) { pbase[i] = tmp[i]; pcursor[i] = tmp[i]; }
}

// ---------------------------------------------------------------------------
// K3: bin edges by partition.  Block b owns a contiguous edge chunk: LDS
// hist -> one global cursor atomicAdd per (block,partition) (~100k total)
// -> line-dense grouped writes (runs of ~8 edges x 8 B).  Entry packing:
// word0 = col | rowLocal<<16 (needs N <= 65536), word1 = fp32 val.
// ---------------------------------------------------------------------------
__global__ __launch_bounds__(256) void afill(
        const int* __restrict__ arow, const int* __restrict__ acol,
        const float* __restrict__ aval, int* __restrict__ pcursor,
        uint2* __restrict__ payload, int E, int P, int chunk) {
    __shared__ int cnt[1024];
    __shared__ int base[1024];
    const int t = threadIdx.x;
    const int lo = blockIdx.x * chunk;
    const int hi = min(E, lo + chunk);
    if (lo >= E) return;
    for (int i = t; i < P; i += 256) cnt[i] = 0;
    __syncthreads();
    for (int e = lo + t; e < hi; e += 256)
        atomicAdd(&cnt[arow[e] >> RTSH], 1);
    __syncthreads();
    for (int i = t; i < P; i += 256) {
        const int c = cnt[i];
        base[i] = c ? atomicAdd(&pcursor[i], c) : 0;
        cnt[i] = 0;
    }
    __syncthreads();
    for (int e = lo + t; e < hi; e += 256) {
        const int r = arow[e];
        const int p = r >> RTSH;
        const int pos = base[p] + atomicAdd(&cnt[p], 1);
        payload[pos] = make_uint2((unsigned)acol[e] | ((unsigned)(r & (RT - 1)) << 16),
                                  __float_as_uint(aval[e]));
    }
}

// ---------------------------------------------------------------------------
// K4: per-partition aggregation.  Block p owns rows [p*RT, p*RT+RT); 32 KB
// fp32 LDS tile; wave-per-edge: 8 B payload read, 256 B xw gather, LDS
// atomic add into tile (2-way bank, free).  Dense ReLU store.  No global
// atomics, no scattered global stores.
// ---------------------------------------------------------------------------
__global__ __launch_bounds__(BT) void bagg(
        const int* __restrict__ pbase, const int* __restrict__ pcount,
        const uint2* __restrict__ payload, const float* __restrict__ xw,
        float* __restrict__ out, int N) {
    __shared__ float tile[RT * OUT_DIM];    // 32 KB
    const int t = threadIdx.x;
    const int lane = t & 63;
    const int wv = t >> 6;                  // 0..7
    const int p = blockIdx.x;
    const int r0 = p << RTSH;

    for (int i = t * 4; i < RT * OUT_DIM; i += BT * 4)
        *(float4*)&tile[i] = make_float4(0.f, 0.f, 0.f, 0.f);
    __syncthreads();

    const int beg = pbase[p];
    const int cnt = pcount[p];
    const int span = (cnt + 7) >> 3;
    const int s = wv * span;
    const int epos = min(cnt, s + span);
    const uint2* pay = payload + beg;

    int k = s;
    for (; k + 4 <= epos; k += 4) {
        uint2 e0 = pay[k], e1 = pay[k + 1], e2 = pay[k + 2], e3 = pay[k + 3];
        float g0 = xw[(size_t)(e0.x & 0xFFFF) * OUT_DIM + lane];
        float g1 = xw[(size_t)(e1.x & 0xFFFF) * OUT_DIM + lane];
        float g2 = xw[(size_t)(e2.x & 0xFFFF) * OUT_DIM + lane];
        float g3 = xw[(size_t)(e3.x & 0xFFFF) * OUT_DIM + lane];
        atomicAdd(&tile[(e0.x >> 16) * OUT_DIM + lane], __uint_as_float(e0.y) * g0);
        atomicAdd(&tile[(e1.x >> 16) * OUT_DIM + lane], __uint_as_float(e1.y) * g1);
        atomicAdd(&tile[(e2.x >> 16) * OUT_DIM + lane], __uint_as_float(e2.y) * g2);
        atomicAdd(&tile[(e3.x >> 16) * OUT_DIM + lane], __uint_as_float(e3.y) * g3);
    }
    for (; k < epos; ++k) {
        uint2 e0 = pay[k];
        float g0 = xw[(size_t)(e0.x & 0xFFFF) * OUT_DIM + lane];
        atomicAdd(&tile[(e0.x >> 16) * OUT_DIM + lane], __uint_as_float(e0.y) * g0);
    }
    __syncthreads();

    for (int i = t; i < RT * OUT_DIM; i += BT) {
        const int row = r0 + (i >> 6);
        if (row < N) {
            const float v = tile[i];
            out[(size_t)row * OUT_DIM + (i & 63)] = v > 0.f ? v : 0.f;
        }
    }
}

// ---------------------------------------------------------------------------
// Fallback: standalone gemm + atomic scatter + relu (always correct).
// ---------------------------------------------------------------------------
__global__ __launch_bounds__(256) void gemm_only(const float* __restrict__ x,
                                                 const float* __restrict__ w,
                                                 float* __restrict__ xw, int N) {
    gemm_body(x, w, xw, N, blockIdx.x);
}

__global__ __launch_bounds__(256) void scatter_edges(
        const int* __restrict__ arow, const int* __restrict__ acol,
        const float* __restrict__ aval, const float* __restrict__ xw,
        float* __restrict__ out, int E) {
    const int lane = threadIdx.x & 63;
    int gw = (blockIdx.x * 256 + (int)threadIdx.x) >> 6;
    const int nw = (gridDim.x * 256) >> 6;
    for (int e = gw; e < E; e += nw) {
        const float m = aval[e] * xw[(size_t)acol[e] * OUT_DIM + lane];
        atomicAdd(&out[(size_t)arow[e] * OUT_DIM + lane], m);
    }
}

__global__ __launch_bounds__(256) void relu_inplace(float* __restrict__ o, int n4) {
    float4* p = (float4*)o;
    int i = blockIdx.x * 256 + threadIdx.x;
    const int stride = gridDim.x * 256;
    for (; i < n4; i += stride) {
        float4 v = p[i];
        v.x = v.x > 0.f ? v.x : 0.f;
        v.y = v.y > 0.f ? v.y : 0.f;
        v.z = v.z > 0.f ? v.z : 0.f;
        v.w = v.w > 0.f ? v.w : 0.f;
        p[i] = v;
    }
}

static inline size_t align256(size_t x) { return (x + 255) & ~(size_t)255; }

extern "C" void kernel_launch(void* const* d_in, const int* in_sizes, int n_in,
                              void* d_out, int out_size, void* d_ws, size_t ws_size,
                              hipStream_t stream) {
    const float* x    = (const float*)d_in[0];
    const float* w    = (const float*)d_in[1];
    const int*   arow = (const int*)d_in[2];
    const int*   acol = (const int*)d_in[3];
    const float* aval = (const float*)d_in[4];
    float*       out  = (float*)d_out;

    const int N = in_sizes[0] / IN_DIM;   // 50000
    const int E = in_sizes[2];            // 800000
    const int P = (N + RT - 1) >> RTSH;   // 391
    const int GB = (N + 63) / 64;         // gemm blocks

    char* ws = (char*)d_ws;
    const size_t szXW  = align256((size_t)N * OUT_DIM * sizeof(float));
    const size_t szP   = align256((size_t)P * sizeof(int));
    const size_t szPay = (size_t)E * sizeof(uint2);
    const size_t need0 = szXW + 3 * szP + szPay;

    float* xw      = (float*)ws;
    int*   pcount  = (int*)(ws + szXW);
    int*   pbase   = (int*)(ws + szXW + szP);
    int*   pcursor = (int*)(ws + szXW + 2 * szP);
    uint2* payload = (uint2*)(ws + szXW + 3 * szP);

    if (ws_size >= need0 && N <= 65536 && P <= 1024) {
        (void)hipMemsetAsync(pcount, 0, (size_t)P * sizeof(int), stream);
        gemm_and_hist<<<GB + 256, 256, 0, stream>>>(x, w, xw, N, arow, pcount, E, GB);
        pscan<<<1, 256, 0, stream>>>(pcount, pbase, pcursor, P);
        const int chunk = (E + 255) / 256;
        afill<<<256, 256, 0, stream>>>(arow, acol, aval, pcursor, payload, E, P, chunk);
        bagg<<<P, BT, 0, stream>>>(pbase, pcount, payload, xw, out, N);
    } else {
        gemm_only<<<GB, 256, 0, stream>>>(x, w, xw, N);
        (void)hipMemsetAsync(d_out, 0, (size_t)out_size * sizeof(float), stream);
        scatter_edges<<<4096, 256, 0, stream>>>(arow, acol, aval, xw, out, E);
        relu_inplace<<<2048, 256, 0, stream>>>(out, out_size / 4);
    }
}

// Round 9
// 186.929 us; speedup vs baseline: 2.5143x; 2.5143x over previous
//
#include <hip/hip_runtime.h>

#define IN_DIM 128
#define OUT_DIM 64
#define PADK 136    // gemm LDS row stride (bf16 elems)
#define RT 128      // rows per partition
#define RTSH 7      // log2(RT)
#define SUB 4       // sub-blocks per partition
#define SR 32       // rows per sub-block (RT/SUB)
#define SEG 1024    // raw edges staged per segment (8 KB)
#define HB 64       // histogram blocks in K1
#define AB 96       // afill blocks

typedef float f32x4 __attribute__((ext_vector_type(4)));
typedef short bf16x8 __attribute__((ext_vector_type(8)));

__device__ __forceinline__ unsigned short f2bf(float f) {   // RNE f32->bf16
    unsigned u = __float_as_uint(f);
    return (unsigned short)((u + 0x7FFFu + ((u >> 16) & 1u)) >> 16);
}
__device__ __forceinline__ float bf2f(unsigned short h) {
    return __uint_as_float((unsigned)h << 16);
}

// ---------------------------------------------------------------------------
// GEMM device body: xw = x@W via split-bf16 MFMA (hi*hi + hi*lo + lo*hi),
// 64 rows per block `blk`.
// ---------------------------------------------------------------------------
__device__ __forceinline__ void gemm_body(const float* __restrict__ x,
                                          const float* __restrict__ w,
                                          float* __restrict__ xw, int N, int blk) {
    __shared__ unsigned short Ahi[64 * PADK];
    __shared__ unsigned short Alo[64 * PADK];
    __shared__ unsigned short Bhi[64 * PADK];   // W^T: [c][k]
    __shared__ unsigned short Blo[64 * PADK];

    const int t = threadIdx.x;
    const int r0 = blk * 64;

    {   // stage W^T hi/lo
        const int c = t >> 2;
        const int kb = (t & 3) * 32;
        for (int k4 = 0; k4 < 32; k4 += 4) {
            ushort4 h, l;
            float v0 = w[(kb + k4 + 0) * OUT_DIM + c];
            float v1 = w[(kb + k4 + 1) * OUT_DIM + c];
            float v2 = w[(kb + k4 + 2) * OUT_DIM + c];
            float v3 = w[(kb + k4 + 3) * OUT_DIM + c];
            h.x = f2bf(v0); l.x = f2bf(v0 - bf2f(h.x));
            h.y = f2bf(v1); l.y = f2bf(v1 - bf2f(h.y));
            h.z = f2bf(v2); l.z = f2bf(v2 - bf2f(h.z));
            h.w = f2bf(v3); l.w = f2bf(v3 - bf2f(h.w));
            *(ushort4*)&Bhi[c * PADK + kb + k4] = h;
            *(ushort4*)&Blo[c * PADK + kb + k4] = l;
        }
    }
    {   // stage x rows hi/lo
        const float4* x4 = (const float4*)x;
        for (int i = 0; i < 8; ++i) {
            const int f = i * 256 + t;
            const int rr = f >> 5;
            const int kk = (f & 31) * 4;
            int row = r0 + rr; if (row >= N) row = N - 1;
            float4 v = x4[(size_t)row * (IN_DIM / 4) + (kk >> 2)];
            ushort4 h, l;
            h.x = f2bf(v.x); l.x = f2bf(v.x - bf2f(h.x));
            h.y = f2bf(v.y); l.y = f2bf(v.y - bf2f(h.y));
            h.z = f2bf(v.z); l.z = f2bf(v.z - bf2f(h.z));
            h.w = f2bf(v.w); l.w = f2bf(v.w - bf2f(h.w));
            *(ushort4*)&Ahi[rr * PADK + kk] = h;
            *(ushort4*)&Alo[rr * PADK + kk] = l;
        }
    }
    __syncthreads();

    const int lane = t & 63;
    const int wv = t >> 6;
    const int m = lane & 15;
    const int quad = lane >> 4;

    bf16x8 ahi[4], alo[4];
#pragma unroll
    for (int ks = 0; ks < 4; ++ks) {
        const int off = (wv * 16 + m) * PADK + ks * 32 + quad * 8;
        ahi[ks] = *(const bf16x8*)&Ahi[off];
        alo[ks] = *(const bf16x8*)&Alo[off];
    }
#pragma unroll
    for (int ct = 0; ct < 4; ++ct) {
        f32x4 acc = {0.f, 0.f, 0.f, 0.f};
#pragma unroll
        for (int ks = 0; ks < 4; ++ks) {
            const int off = (ct * 16 + m) * PADK + ks * 32 + quad * 8;
            bf16x8 bh = *(const bf16x8*)&Bhi[off];
            bf16x8 bl = *(const bf16x8*)&Blo[off];
            acc = __builtin_amdgcn_mfma_f32_16x16x32_bf16(alo[ks], bh, acc, 0, 0, 0);
            acc = __builtin_amdgcn_mfma_f32_16x16x32_bf16(ahi[ks], bl, acc, 0, 0, 0);
            acc = __builtin_amdgcn_mfma_f32_16x16x32_bf16(ahi[ks], bh, acc, 0, 0, 0);
        }
#pragma unroll
        for (int i = 0; i < 4; ++i) {
            const int row = r0 + wv * 16 + quad * 4 + i;
            if (row < N) xw[(size_t)row * OUT_DIM + ct * 16 + m] = acc[i];
        }
    }
}

// ---------------------------------------------------------------------------
// K1: blocks [0,GB) run the GEMM; blocks [GB,GB+HB) histogram edge
// destination partitions (LDS hist -> P global int atomics per block).
// ---------------------------------------------------------------------------
__global__ __launch_bounds__(256) void gemm_and_hist(
        const float* __restrict__ x, const float* __restrict__ w,
        float* __restrict__ xw, int N,
        const int* __restrict__ arow, int* __restrict__ pcount, int E, int GB) {
    if ((int)blockIdx.x < GB) {
        gemm_body(x, w, xw, N, blockIdx.x);
    } else {
        __shared__ int cnt[1024];
        const int P = (N + RT - 1) >> RTSH;
        const int t = threadIdx.x;
        for (int i = t; i < P; i += 256) cnt[i] = 0;
        __syncthreads();
        const int hb = blockIdx.x - GB;              // 0..HB-1
        for (int e = hb * 256 + t; e < E; e += HB * 256)
            atomicAdd(&cnt[arow[e] >> RTSH], 1);
        __syncthreads();
        for (int i = t; i < P; i += 256)
            if (cnt[i]) atomicAdd(&pcount[i], cnt[i]);
    }
}

// ---------------------------------------------------------------------------
// K2: exclusive scan of P partition counts (P <= 1024).
// ---------------------------------------------------------------------------
__global__ __launch_bounds__(256) void pscan(const int* __restrict__ pcount,
                                             int* __restrict__ pbase,
                                             int* __restrict__ pcursor, int P) {
    __shared__ int tmp[1024];
    const int t = threadIdx.x;
    for (int i = t; i < P; i += 256) tmp[i] = pcount[i];
    __syncthreads();
    if (t == 0) {
        int run = 0;
        for (int i = 0; i < P; ++i) { int v = tmp[i]; tmp[i] = run; run += v; }
    }
    __syncthreads();
    for (int i = t; i < P; i += 256) { pbase[i] = tmp[i]; pcursor[i] = tmp[i]; }
}

// ---------------------------------------------------------------------------
// K3: bin edges by partition.  AB blocks, each owns a contiguous edge chunk:
// LDS hist -> one global cursor atomicAdd per (block,partition) -> grouped
// writes in runs of ~E/(AB*P) edges (~21 -> line-dense; block's write set is
// L2-resident so lines fill before eviction).  word0 = col | rowLocal<<16
// (needs N <= 65536), word1 = fp32 val.
// ---------------------------------------------------------------------------
__global__ __launch_bounds__(256) void afill(
        const int* __restrict__ arow, const int* __restrict__ acol,
        const float* __restrict__ aval, int* __restrict__ pcursor,
        uint2* __restrict__ payload, int E, int P, int chunk) {
    __shared__ int cnt[1024];
    __shared__ int base[1024];
    const int t = threadIdx.x;
    const int lo = blockIdx.x * chunk;
    const int hi = min(E, lo + chunk);
    if (lo >= E) return;
    for (int i = t; i < P; i += 256) cnt[i] = 0;
    __syncthreads();
    for (int e = lo + t; e < hi; e += 256)
        atomicAdd(&cnt[arow[e] >> RTSH], 1);
    __syncthreads();
    for (int i = t; i < P; i += 256) {
        const int c = cnt[i];
        base[i] = c ? atomicAdd(&pcursor[i], c) : 0;
        cnt[i] = 0;
    }
    __syncthreads();
    for (int e = lo + t; e < hi; e += 256) {
        const int r = arow[e];
        const int p = r >> RTSH;
        const int pos = base[p] + atomicAdd(&cnt[p], 1);
        payload[pos] = make_uint2((unsigned)acol[e] | ((unsigned)(r & (RT - 1)) << 16),
                                  __float_as_uint(aval[e]));
    }
}

// ---------------------------------------------------------------------------
// K4: sub-partitioned pull.  Block = (partition p, sub s); owns 32 rows.
// Per 1024-edge segment of p's payload: count in-range rows (LDS INT
// atomics, native), tiny scan, place into row-sorted LDS stage, then
// per-row REGISTER accumulation with 4-edge-ILP gathers.  Fused ReLU store.
// No float atomics of any kind; grid = P*4 blocks (all co-resident).
// ---------------------------------------------------------------------------
__global__ __launch_bounds__(256) void bagg(
        const int* __restrict__ pbase, const int* __restrict__ pcount,
        const uint2* __restrict__ payload, const float* __restrict__ xw,
        float* __restrict__ out, int N) {
    __shared__ uint2 stage[SEG];       // 8 KB
    __shared__ int cnt2[SR + 1];
    __shared__ int place[SR];
    const int t = threadIdx.x;
    const int lane = t & 63;
    const int wv = t >> 6;             // 0..3
    const int p = blockIdx.x >> 2;
    const int sub = blockIdx.x & 3;
    const int rbase = (p << RTSH) + sub * SR;

    float acc[8];
#pragma unroll
    for (int i = 0; i < 8; ++i) acc[i] = 0.f;

    const int beg = pbase[p];
    const int cnt = pcount[p];

    for (int off = 0; off < cnt; off += SEG) {
        const int n = min(SEG, cnt - off);
        if (t <= SR) cnt2[t] = 0;
        if (t < SR) place[t] = 0;
        __syncthreads();
        // pass 1: count this sub-block's rows in the segment
        for (int i = t; i < n; i += 256) {
            const unsigned rl = payload[beg + off + i].x >> 16;   // 0..127
            if ((int)(rl >> 5) == sub) atomicAdd(&cnt2[rl & 31], 1);
        }
        __syncthreads();
        if (t == 0) {                   // exclusive scan of 32 bins
            int run = 0;
            for (int i = 0; i < SR; ++i) { int v = cnt2[i]; cnt2[i] = run; run += v; }
            cnt2[SR] = run;
        }
        __syncthreads();
        // pass 2: place (payload re-read is L2-hot)
        for (int i = t; i < n; i += 256) {
            const uint2 e = payload[beg + off + i];
            const unsigned rl = e.x >> 16;
            if ((int)(rl >> 5) == sub) {
                const int pos = cnt2[rl & 31] + atomicAdd(&place[rl & 31], 1);
                stage[pos] = e;
            }
        }
        __syncthreads();
        // pull: wave wv owns local rows [wv*8, wv*8+8)
#pragma unroll
        for (int lr = 0; lr < 8; ++lr) {
            const int row = wv * 8 + lr;
            int j = cnt2[row];
            const int end = cnt2[row + 1];
            float a = acc[lr];
            for (; j + 4 <= end; j += 4) {
                uint2 e0 = stage[j], e1 = stage[j+1], e2 = stage[j+2], e3 = stage[j+3];
                float g0 = xw[(size_t)(e0.x & 0xFFFF) * OUT_DIM + lane];
                float g1 = xw[(size_t)(e1.x & 0xFFFF) * OUT_DIM + lane];
                float g2 = xw[(size_t)(e2.x & 0xFFFF) * OUT_DIM + lane];
                float g3 = xw[(size_t)(e3.x & 0xFFFF) * OUT_DIM + lane];
                a = fmaf(__uint_as_float(e0.y), g0, a);
                a = fmaf(__uint_as_float(e1.y), g1, a);
                a = fmaf(__uint_as_float(e2.y), g2, a);
                a = fmaf(__uint_as_float(e3.y), g3, a);
            }
            for (; j < end; ++j) {
                uint2 e0 = stage[j];
                a = fmaf(__uint_as_float(e0.y),
                         xw[(size_t)(e0.x & 0xFFFF) * OUT_DIM + lane], a);
            }
            acc[lr] = a;
        }
        __syncthreads();   // protect counters before next segment
    }
#pragma unroll
    for (int lr = 0; lr < 8; ++lr) {
        const int row = rbase + wv * 8 + lr;
        if (row < N) {
            const float v = acc[lr];
            out[(size_t)row * OUT_DIM + lane] = v > 0.f ? v : 0.f;
        }
    }
}

// ---------------------------------------------------------------------------
// Fallback: standalone gemm + atomic scatter + relu (always correct).
// ---------------------------------------------------------------------------
__global__ __launch_bounds__(256) void gemm_only(const float* __restrict__ x,
                                                 const float* __restrict__ w,
                                                 float* __restrict__ xw, int N) {
    gemm_body(x, w, xw, N, blockIdx.x);
}

__global__ __launch_bounds__(256) void scatter_edges(
        const int* __restrict__ arow, const int* __restrict__ acol,
        const float* __restrict__ aval, const float* __restrict__ xw,
        float* __restrict__ out, int E) {
    const int lane = threadIdx.x & 63;
    int gw = (blockIdx.x * 256 + (int)threadIdx.x) >> 6;
    const int nw = (gridDim.x * 256) >> 6;
    for (int e = gw; e < E; e += nw) {
        const float m = aval[e] * xw[(size_t)acol[e] * OUT_DIM + lane];
        atomicAdd(&out[(size_t)arow[e] * OUT_DIM + lane], m);
    }
}

__global__ __launch_bounds__(256) void relu_inplace(float* __restrict__ o, int n4) {
    float4* p = (float4*)o;
    int i = blockIdx.x * 256 + threadIdx.x;
    const int stride = gridDim.x * 256;
    for (; i < n4; i += stride) {
        float4 v = p[i];
        v.x = v.x > 0.f ? v.x : 0.f;
        v.y = v.y > 0.f ? v.y : 0.f;
        v.z = v.z > 0.f ? v.z : 0.f;
        v.w = v.w > 0.f ? v.w : 0.f;
        p[i] = v;
    }
}

static inline size_t align256(size_t x) { return (x + 255) & ~(size_t)255; }

extern "C" void kernel_launch(void* const* d_in, const int* in_sizes, int n_in,
                              void* d_out, int out_size, void* d_ws, size_t ws_size,
                              hipStream_t stream) {
    const float* x    = (const float*)d_in[0];
    const float* w    = (const float*)d_in[1];
    const int*   arow = (const int*)d_in[2];
    const int*   acol = (const int*)d_in[3];
    const float* aval = (const float*)d_in[4];
    float*       out  = (float*)d_out;

    const int N = in_sizes[0] / IN_DIM;   // 50000
    const int E = in_sizes[2];            // 800000
    const int P = (N + RT - 1) >> RTSH;   // 391
    const int GB = (N + 63) / 64;         // gemm blocks

    char* ws = (char*)d_ws;
    const size_t szXW  = align256((size_t)N * OUT_DIM * sizeof(float));
    const size_t szP   = align256((size_t)P * sizeof(int));
    const size_t szPay = (size_t)E * sizeof(uint2);
    const size_t need0 = szXW + 3 * szP + szPay;

    float* xw      = (float*)ws;
    int*   pcount  = (int*)(ws + szXW);
    int*   pbase   = (int*)(ws + szXW + szP);
    int*   pcursor = (int*)(ws + szXW + 2 * szP);
    uint2* payload = (uint2*)(ws + szXW + 3 * szP);

    if (ws_size >= need0 && N <= 65536 && P <= 1024) {
        (void)hipMemsetAsync(pcount, 0, (size_t)P * sizeof(int), stream);
        gemm_and_hist<<<GB + HB, 256, 0, stream>>>(x, w, xw, N, arow, pcount, E, GB);
        pscan<<<1, 256, 0, stream>>>(pcount, pbase, pcursor, P);
        const int chunk = (E + AB - 1) / AB;
        afill<<<AB, 256, 0, stream>>>(arow, acol, aval, pcursor, payload, E, P, chunk);
        bagg<<<P * SUB, 256, 0, stream>>>(pbase, pcount, payload, xw, out, N);
    } else {
        gemm_only<<<GB, 256, 0, stream>>>(x, w, xw, N);
        (void)hipMemsetAsync(d_out, 0, (size_t)out_size * sizeof(float), stream);
        scatter_edges<<<4096, 256, 0, stream>>>(arow, acol, aval, xw, out, E);
        relu_inplace<<<2048, 256, 0, stream>>>(out, out_size / 4);
    }
}